// Round 5
// baseline (91.604 us; speedup 1.0000x reference)
//
#include <hip/hip_runtime.h>

// Problem: N=512, D=512, fp32 in/out.
// pre[i][c] = he @ W0 half-slices  -> bf16 MFMA, f32 operands cvt'd in-register
//                                     (fused prep; aux blocks build hebT f16)
// p[i,j] = sum_h relu(CI[i,h]+CJ[j,h])*w1[h] -> packed f16 + v_dot2_f32_f16 (f32 accum)
// a = softmax_rows(p); out = a @ he -> f16 MFMA
// W1_b dropped: softmax-invariant.
//
// ws: Ppart[16][512][512] f16 | CI[512*512] f16 | CJ[512*512] f16 |
//     hebT[512*512] f16 | Awb[512*512] f16

using bf16x8 = __attribute__((ext_vector_type(8))) short;
using f32x4  = __attribute__((ext_vector_type(4))) float;
using f16x2  = __attribute__((ext_vector_type(2))) _Float16;
using f16x4  = __attribute__((ext_vector_type(4))) _Float16;
using f16x8  = __attribute__((ext_vector_type(8))) _Float16;

#define SC_STR 68  // f16x2 units (4B): 64 + 4 pad -> <=2-way LDS conflicts (free)

__device__ __forceinline__ unsigned short f2h(float x) {
    union { _Float16 h; unsigned short u; } c;
    c.h = (_Float16)x;                 // RNE
    return c.u;
}

// pack 8 f32 -> bf16x8 via v_cvt_pk_bf16_f32 (RNE)
__device__ __forceinline__ bf16x8 cvt8(float4 lo, float4 hi) {
    union { bf16x8 v; unsigned int u[4]; } r;
    asm("v_cvt_pk_bf16_f32 %0, %1, %2" : "=v"(r.u[0]) : "v"(lo.x), "v"(lo.y));
    asm("v_cvt_pk_bf16_f32 %0, %1, %2" : "=v"(r.u[1]) : "v"(lo.z), "v"(lo.w));
    asm("v_cvt_pk_bf16_f32 %0, %1, %2" : "=v"(r.u[2]) : "v"(hi.x), "v"(hi.y));
    asm("v_cvt_pk_bf16_f32 %0, %1, %2" : "=v"(r.u[3]) : "v"(hi.z), "v"(hi.w));
    return r.v;
}

// ---------------------------------------------------------------------------
// Kernel 1 (fused prep+pre): blocks 0..511: CI/CJ GEMM, 1 wave per 32x32 tile,
// f32 operands from L2 converted in-register to bf16 for MFMA.
// Blocks 512..575: he -> hebT (f16 transposed), one 64x64 tile each.
// grid 576, block 64.
__global__ __launch_bounds__(64) void k_preA(const float* __restrict__ he,
                                             const float* __restrict__ w0,
                                             const float* __restrict__ b0,
                                             _Float16* __restrict__ CI,
                                             _Float16* __restrict__ CJ,
                                             unsigned short* __restrict__ hebT) {
    const int bx = blockIdx.x;
    const int l = threadIdx.x;

    if (bx >= 512) {   // ---- transpose duty: he -> hebT (f16) ----
        __shared__ unsigned short T[64][65];
        const int t = bx - 512;
        const int r0 = (t >> 3) * 64, c0 = (t & 7) * 64;
        #pragma unroll
        for (int rep = 0; rep < 16; ++rep) {
            int f = l + rep * 64;
            int row = f >> 4, col = (f & 15) * 4;
            float4 a = *(const float4*)&he[(r0 + row) * 512 + c0 + col];
            T[row][col + 0] = f2h(a.x); T[row][col + 1] = f2h(a.y);
            T[row][col + 2] = f2h(a.z); T[row][col + 3] = f2h(a.w);
        }
        __syncthreads();
        #pragma unroll
        for (int rep = 0; rep < 16; ++rep) {
            int f = l + rep * 64;
            int trow = f >> 4, tcol = (f & 15) * 4;
            ushort4 v = make_ushort4(T[tcol + 0][trow], T[tcol + 1][trow],
                                     T[tcol + 2][trow], T[tcol + 3][trow]);
            *(ushort4*)&hebT[(c0 + trow) * 512 + r0 + tcol] = v;
        }
        return;
    }

    const int c0 = (bx & 31) * 32;     // 0..1023
    const int i0 = (bx >> 5) * 32;     // 0..511
    const int r16 = l & 15;
    const int k0l = (l >> 4) * 8;
    const int hrow0 = c0 & 511;
    const int dofs = (c0 >= 512) ? 512 : 0;

    f32x4 acc[2][2] = {};
    const float* pa0 = he + (i0 + r16) * 512;
    const float* pa1 = pa0 + 16 * 512;
    const float* pb0 = w0 + (hrow0 + r16) * 1024 + dofs;
    const float* pb1 = pb0 + 16 * 1024;

    #pragma unroll
    for (int ks = 0; ks < 16; ++ks) {
        const int k0 = ks * 32 + k0l;
        bf16x8 a0 = cvt8(*(const float4*)(pa0 + k0), *(const float4*)(pa0 + k0 + 4));
        bf16x8 a1 = cvt8(*(const float4*)(pa1 + k0), *(const float4*)(pa1 + k0 + 4));
        bf16x8 b0v = cvt8(*(const float4*)(pb0 + k0), *(const float4*)(pb0 + k0 + 4));
        bf16x8 b1v = cvt8(*(const float4*)(pb1 + k0), *(const float4*)(pb1 + k0 + 4));
        acc[0][0] = __builtin_amdgcn_mfma_f32_16x16x32_bf16(a0, b0v, acc[0][0], 0, 0, 0);
        acc[0][1] = __builtin_amdgcn_mfma_f32_16x16x32_bf16(a0, b1v, acc[0][1], 0, 0, 0);
        acc[1][0] = __builtin_amdgcn_mfma_f32_16x16x32_bf16(a1, b0v, acc[1][0], 0, 0, 0);
        acc[1][1] = __builtin_amdgcn_mfma_f32_16x16x32_bf16(a1, b1v, acc[1][1], 0, 0, 0);
    }
    // C/D layout: col = lane&15, row = (lane>>4)*4 + reg
    const int orow = (l >> 4) * 4;
    if (dofs) {
        const float bb0 = b0[hrow0 + r16];
        const float bb1 = b0[hrow0 + 16 + r16];
        #pragma unroll
        for (int ti = 0; ti < 2; ++ti)
            #pragma unroll
            for (int tj = 0; tj < 2; ++tj) {
                const float bb = tj ? bb1 : bb0;
                #pragma unroll
                for (int r = 0; r < 4; ++r)
                    CJ[(i0 + ti * 16 + orow + r) * 512 + hrow0 + tj * 16 + r16] =
                        (_Float16)(acc[ti][tj][r] + bb);
            }
    } else {
        #pragma unroll
        for (int ti = 0; ti < 2; ++ti)
            #pragma unroll
            for (int tj = 0; tj < 2; ++tj)
                #pragma unroll
                for (int r = 0; r < 4; ++r)
                    CI[(i0 + ti * 16 + orow + r) * 512 + c0 + tj * 16 + r16] =
                        (_Float16)acc[ti][tj][r];
    }
}

// ---------------------------------------------------------------------------
// Kernel 2: Ppart[hs][i][j] = (f16) sum_{h in 32-slice hs} relu(CI[i,h]+CJ[j,h]) * w1[h]
// grid (8 j, 8 i, 16 hs), block 256, 64x64 tile, 4x4 micro, single stage phase.
__global__ __launch_bounds__(256) void k_score(const _Float16* __restrict__ CI,
                                               const _Float16* __restrict__ CJ,
                                               const float* __restrict__ w1,
                                               _Float16* __restrict__ Ppart) {
    const int tid = threadIdx.x;
    const int tx = tid & 15, ty = tid >> 4;
    const int j0 = blockIdx.x * 64;
    const int i0 = blockIdx.y * 64;
    const int hb = blockIdx.z * 32;

    __shared__ __align__(16) f16x2 As2[16 * SC_STR];  // [h-pair][i]
    __shared__ __align__(16) f16x2 Bs2[16 * SC_STR];  // [h-pair][j]
    __shared__ f16x2 Ws2[16];

    const f16x2 fz = {(_Float16)0, (_Float16)0};
    float acc[4][4] = {};

    // stage: each thread reads 8 halves (16B) of one row, repacks into 4 h-pairs
    {
        const int row = tid >> 2;
        const int hc = (tid & 3) * 8;
        const int hp = hc >> 1;
        f16x8 av = *(const f16x8*)&CI[(i0 + row) * 512 + hb + hc];
        As2[(hp + 0) * SC_STR + row] = __builtin_shufflevector(av, av, 0, 1);
        As2[(hp + 1) * SC_STR + row] = __builtin_shufflevector(av, av, 2, 3);
        As2[(hp + 2) * SC_STR + row] = __builtin_shufflevector(av, av, 4, 5);
        As2[(hp + 3) * SC_STR + row] = __builtin_shufflevector(av, av, 6, 7);
        f16x8 bv = *(const f16x8*)&CJ[(j0 + row) * 512 + hb + hc];
        Bs2[(hp + 0) * SC_STR + row] = __builtin_shufflevector(bv, bv, 0, 1);
        Bs2[(hp + 1) * SC_STR + row] = __builtin_shufflevector(bv, bv, 2, 3);
        Bs2[(hp + 2) * SC_STR + row] = __builtin_shufflevector(bv, bv, 4, 5);
        Bs2[(hp + 3) * SC_STR + row] = __builtin_shufflevector(bv, bv, 6, 7);
    }
    if (tid < 16) {
        float2 w = *(const float2*)&w1[hb + 2 * tid];
        f16x2 wp = {(_Float16)w.x, (_Float16)w.y};
        Ws2[tid] = wp;
    }
    __syncthreads();
    #pragma unroll
    for (int k = 0; k < 16; ++k) {
        f16x8 a8 = *(const f16x8*)&As2[k * SC_STR + 4 * ty];
        f16x8 b8 = *(const f16x8*)&Bs2[k * SC_STR + 4 * tx];
        const f16x2 w = Ws2[k];
        f16x2 ap[4] = { __builtin_shufflevector(a8, a8, 0, 1),
                        __builtin_shufflevector(a8, a8, 2, 3),
                        __builtin_shufflevector(a8, a8, 4, 5),
                        __builtin_shufflevector(a8, a8, 6, 7) };
        f16x2 bp[4] = { __builtin_shufflevector(b8, b8, 0, 1),
                        __builtin_shufflevector(b8, b8, 2, 3),
                        __builtin_shufflevector(b8, b8, 4, 5),
                        __builtin_shufflevector(b8, b8, 6, 7) };
        #pragma unroll
        for (int ii = 0; ii < 4; ++ii)
            #pragma unroll
            for (int jj = 0; jj < 4; ++jj) {
                f16x2 s = ap[ii] + bp[jj];
                s = __builtin_elementwise_max(s, fz);
                acc[ii][jj] = __builtin_amdgcn_fdot2(s, w, acc[ii][jj], false);
            }
    }
    _Float16* outp = Ppart + (size_t)blockIdx.z * 512 * 512;
    #pragma unroll
    for (int ii = 0; ii < 4; ++ii) {
        f16x4 v = { (_Float16)acc[ii][0], (_Float16)acc[ii][1],
                    (_Float16)acc[ii][2], (_Float16)acc[ii][3] };
        *(f16x4*)&outp[(i0 + 4 * ty + ii) * 512 + j0 + 4 * tx] = v;
    }
}

// ---------------------------------------------------------------------------
// Kernel 3: reduce 16 f16 P-partials, row softmax -> Awb[i][j] (f16). grid(512), block 256.
__global__ __launch_bounds__(256) void k_softmax(const _Float16* __restrict__ Ppart,
                                                 _Float16* __restrict__ Awb) {
    const int i = blockIdx.x;
    const int tid = threadIdx.x;
    float p0 = 0.f, p1 = 0.f;
    #pragma unroll
    for (int s = 0; s < 16; ++s) {
        p0 += (float)Ppart[s * 262144 + i * 512 + tid];
        p1 += (float)Ppart[s * 262144 + i * 512 + tid + 256];
    }
    __shared__ float red[256];
    red[tid] = fmaxf(p0, p1);
    __syncthreads();
    for (int s = 128; s > 0; s >>= 1) {
        if (tid < s) red[tid] = fmaxf(red[tid], red[tid + s]);
        __syncthreads();
    }
    const float m = red[0];
    __syncthreads();
    const float e0 = __expf(p0 - m);
    const float e1 = __expf(p1 - m);
    red[tid] = e0 + e1;
    __syncthreads();
    for (int s = 128; s > 0; s >>= 1) {
        if (tid < s) red[tid] += red[tid + s];
        __syncthreads();
    }
    const float inv = 1.0f / red[0];
    Awb[i * 512 + tid] = (_Float16)(e0 * inv);
    Awb[i * 512 + tid + 256] = (_Float16)(e1 * inv);
}

// ---------------------------------------------------------------------------
// Kernel 4: out = Aw @ he via f16 MFMA. 1 wave per 16x32 tile.
// grid (16 d-tiles, 32 i-tiles), block 64.
__global__ __launch_bounds__(64) void k_outM(const _Float16* __restrict__ Awb,
                                             const _Float16* __restrict__ hebT,
                                             float* __restrict__ outp) {
    const int l = threadIdx.x;
    const int d0 = blockIdx.x * 32;
    const int i0 = blockIdx.y * 16;
    const int r16 = l & 15;
    const int k0l = (l >> 4) * 8;

    f32x4 acc[2] = {};
    const _Float16* pa  = Awb  + (i0 + r16) * 512;
    const _Float16* pb0 = hebT + (d0 + r16) * 512;
    const _Float16* pb1 = hebT + (d0 + 16 + r16) * 512;

    #pragma unroll
    for (int ks = 0; ks < 16; ++ks) {
        const int k0 = ks * 32 + k0l;
        f16x8 a  = *(const f16x8*)(pa + k0);
        f16x8 b0 = *(const f16x8*)(pb0 + k0);
        f16x8 b1 = *(const f16x8*)(pb1 + k0);
        acc[0] = __builtin_amdgcn_mfma_f32_16x16x32_f16(a, b0, acc[0], 0, 0, 0);
        acc[1] = __builtin_amdgcn_mfma_f32_16x16x32_f16(a, b1, acc[1], 0, 0, 0);
    }
    const int orow = (l >> 4) * 4;
    #pragma unroll
    for (int tj = 0; tj < 2; ++tj)
        #pragma unroll
        for (int r = 0; r < 4; ++r)
            outp[(i0 + orow + r) * 512 + d0 + tj * 16 + r16] = acc[tj][r];
}

extern "C" void kernel_launch(void* const* d_in, const int* in_sizes, int n_in,
                              void* d_out, int out_size, void* d_ws, size_t ws_size,
                              hipStream_t stream) {
    const float* he = (const float*)d_in[0];   // (512, 512)
    const float* w0 = (const float*)d_in[1];   // (512, 1024)
    const float* b0 = (const float*)d_in[2];   // (512,)
    const float* w1 = (const float*)d_in[3];   // (1, 512)
    // d_in[4] = W1_b: softmax-invariant, intentionally unused.
    float* outp = (float*)d_out;               // (512, 512)

    _Float16* Ppart = (_Float16*)d_ws;                      // 16*512*512 f16
    _Float16* CI = Ppart + 16 * 512 * 512;                  // 512*512 f16
    _Float16* CJ = CI + 512 * 512;                          // 512*512 f16
    unsigned short* hebT = (unsigned short*)(CJ + 512 * 512);  // 512*512 f16 bits
    _Float16* Awb = (_Float16*)(hebT + 512 * 512);          // 512*512 f16

    k_preA   <<<dim3(576),      64,  0, stream>>>(he, w0, b0, CI, CJ, hebT);
    k_score  <<<dim3(8, 8, 16), 256, 0, stream>>>(CI, CJ, w1, Ppart);
    k_softmax<<<dim3(512),      256, 0, stream>>>(Ppart, Awb);
    k_outM   <<<dim3(16, 32),   64,  0, stream>>>(Awb, (const _Float16*)hebT, outp);
}

// Round 6
// 90.170 us; speedup vs baseline: 1.0159x; 1.0159x over previous
//
#include <hip/hip_runtime.h>

// Problem: N=512, D=512, fp32 in/out.
// pre[i][c] = he @ W0 half-slices            -> bf16 MFMA -> CI/CJ in f16 (bias folded into CJ)
// p[i,j] = sum_h relu(CI[i,h] + CJ[j,h]) * w1[h] -> packed f16 + v_dot2_f32_f16 (f32 accum)
// a = softmax_rows(p); out = a @ he          -> f16 MFMA (Awb, hebT in f16)
// W1_b dropped: softmax-invariant.
//
// ws layout: Ppart[8][512][512] f16 | CI[512*512] f16 | CJ[512*512] f16 |
//            heb[512*512] bf16 | hebT[512*512] f16 | w0b[512*1024] bf16 | Awb[512*512] f16

using bf16x8 = __attribute__((ext_vector_type(8))) short;
using f32x4  = __attribute__((ext_vector_type(4))) float;
using f16x2  = __attribute__((ext_vector_type(2))) _Float16;
using f16x4  = __attribute__((ext_vector_type(4))) _Float16;
using f16x8  = __attribute__((ext_vector_type(8))) _Float16;

#define SC_STR 68  // f16x2 units (4B): 64 + 4 pad -> <=2-way LDS conflicts (free)

__device__ __forceinline__ unsigned short f2bf(float x) {
    unsigned int u = __float_as_uint(x);
    u += 0x7fffu + ((u >> 16) & 1u);   // RNE
    return (unsigned short)(u >> 16);
}

__device__ __forceinline__ unsigned short f2h(float x) {
    _Float16 h = (_Float16)x;          // RNE
    union { _Float16 h; unsigned short u; } c; c.h = h;
    return c.u;
}

// ---------------------------------------------------------------------------
// Kernel 0: he -> heb (bf16) + hebT (f16 transposed); w0 -> w0b (bf16).
// grid (8,8,3), block 256.
__global__ __launch_bounds__(256) void k_prep(const float* __restrict__ he,
                                              const float* __restrict__ w0,
                                              unsigned short* __restrict__ heb,
                                              _Float16* __restrict__ hebT,
                                              unsigned short* __restrict__ w0b) {
    const int tid = threadIdx.x;
    if (blockIdx.z == 0) {
        __shared__ unsigned short T[64][65];   // f16 bits
        const int r0 = blockIdx.y * 64, c0 = blockIdx.x * 64;
        #pragma unroll
        for (int rep = 0; rep < 4; ++rep) {
            int f = tid + rep * 256;
            int row = f >> 4, col = (f & 15) * 4;
            float4 a = *(const float4*)&he[(r0 + row) * 512 + c0 + col];
            *(ushort4*)&heb[(r0 + row) * 512 + c0 + col] =
                make_ushort4(f2bf(a.x), f2bf(a.y), f2bf(a.z), f2bf(a.w));
            T[row][col + 0] = f2h(a.x); T[row][col + 1] = f2h(a.y);
            T[row][col + 2] = f2h(a.z); T[row][col + 3] = f2h(a.w);
        }
        __syncthreads();
        #pragma unroll
        for (int rep = 0; rep < 4; ++rep) {
            int f = tid + rep * 256;
            int trow = f >> 4, tcol = (f & 15) * 4;
            ushort4 v = make_ushort4(T[tcol + 0][trow], T[tcol + 1][trow],
                                     T[tcol + 2][trow], T[tcol + 3][trow]);
            *(ushort4*)&hebT[(c0 + trow) * 512 + r0 + tcol] = v;
        }
    } else {
        const int r0 = blockIdx.y * 64, c0 = blockIdx.x * 64 + (blockIdx.z - 1) * 512;
        #pragma unroll
        for (int rep = 0; rep < 4; ++rep) {
            int f = tid + rep * 256;
            int row = f >> 4, col = (f & 15) * 4;
            float4 a = *(const float4*)&w0[(r0 + row) * 1024 + c0 + col];
            *(ushort4*)&w0b[(r0 + row) * 1024 + c0 + col] =
                make_ushort4(f2bf(a.x), f2bf(a.y), f2bf(a.z), f2bf(a.w));
        }
    }
}

// ---------------------------------------------------------------------------
// Kernel 1: CI[i][h] = (f16) sum_d he[i,d]*W0[h,d];  CJ[j][h] = (f16)(... + b0[h])
// 1 wave per 32x32 tile (2x2 of 16x16x32 bf16 mfma), frags straight from L2.
// grid (32 c-tiles, 16 i-tiles), block 64.
__global__ __launch_bounds__(64) void k_preA(const unsigned short* __restrict__ heb,
                                             const unsigned short* __restrict__ w0b,
                                             const float* __restrict__ b0,
                                             _Float16* __restrict__ CI,
                                             _Float16* __restrict__ CJ) {
    const int l = threadIdx.x;
    const int c0 = blockIdx.x * 32;
    const int i0 = blockIdx.y * 32;
    const int r16 = l & 15;
    const int k0l = (l >> 4) * 8;
    const int hrow0 = c0 & 511;
    const int dofs = (c0 >= 512) ? 512 : 0;

    f32x4 acc[2][2] = {};
    const unsigned short* pa0 = heb + (i0 + r16) * 512;
    const unsigned short* pa1 = heb + (i0 + 16 + r16) * 512;
    const unsigned short* pb0 = w0b + (hrow0 + r16) * 1024 + dofs;
    const unsigned short* pb1 = w0b + (hrow0 + 16 + r16) * 1024 + dofs;

    #pragma unroll
    for (int ks = 0; ks < 16; ++ks) {
        const int k0 = ks * 32 + k0l;
        bf16x8 a0 = *(const bf16x8*)(pa0 + k0);
        bf16x8 a1 = *(const bf16x8*)(pa1 + k0);
        bf16x8 b0v = *(const bf16x8*)(pb0 + k0);
        bf16x8 b1v = *(const bf16x8*)(pb1 + k0);
        acc[0][0] = __builtin_amdgcn_mfma_f32_16x16x32_bf16(a0, b0v, acc[0][0], 0, 0, 0);
        acc[0][1] = __builtin_amdgcn_mfma_f32_16x16x32_bf16(a0, b1v, acc[0][1], 0, 0, 0);
        acc[1][0] = __builtin_amdgcn_mfma_f32_16x16x32_bf16(a1, b0v, acc[1][0], 0, 0, 0);
        acc[1][1] = __builtin_amdgcn_mfma_f32_16x16x32_bf16(a1, b1v, acc[1][1], 0, 0, 0);
    }
    // C/D layout: col = lane&15, row = (lane>>4)*4 + reg
    const int orow = (l >> 4) * 4;
    if (dofs) {
        const float bb0 = b0[hrow0 + r16];
        const float bb1 = b0[hrow0 + 16 + r16];
        #pragma unroll
        for (int ti = 0; ti < 2; ++ti)
            #pragma unroll
            for (int tj = 0; tj < 2; ++tj) {
                const float bb = tj ? bb1 : bb0;
                #pragma unroll
                for (int r = 0; r < 4; ++r)
                    CJ[(i0 + ti * 16 + orow + r) * 512 + hrow0 + tj * 16 + r16] =
                        (_Float16)(acc[ti][tj][r] + bb);
            }
    } else {
        #pragma unroll
        for (int ti = 0; ti < 2; ++ti)
            #pragma unroll
            for (int tj = 0; tj < 2; ++tj)
                #pragma unroll
                for (int r = 0; r < 4; ++r)
                    CI[(i0 + ti * 16 + orow + r) * 512 + c0 + tj * 16 + r16] =
                        (_Float16)acc[ti][tj][r];
    }
}

// ---------------------------------------------------------------------------
// Kernel 2: Ppart[hs][i][j] = (f16) sum_{h in slice hs} relu(CI[i,h]+CJ[j,h]) * w1[h]
// Packed f16 pairs along h; v_pk_add + v_pk_max + v_dot2_f32_f16 (f32 accum).
// grid (8 j-tiles, 8 i-tiles, 8 h-slices of 64), block 256, 64x64 tile, 4x4 micro.
__global__ __launch_bounds__(256) void k_score(const _Float16* __restrict__ CI,
                                               const _Float16* __restrict__ CJ,
                                               const float* __restrict__ w1,
                                               _Float16* __restrict__ Ppart) {
    const int tid = threadIdx.x;
    const int tx = tid & 15, ty = tid >> 4;
    const int j0 = blockIdx.x * 64;
    const int i0 = blockIdx.y * 64;
    const int hs = blockIdx.z;

    __shared__ __align__(16) f16x2 As2[16 * SC_STR];  // [h-pair][i]
    __shared__ __align__(16) f16x2 Bs2[16 * SC_STR];  // [h-pair][j]
    __shared__ f16x2 Ws2[16];

    const f16x2 fz = {(_Float16)0, (_Float16)0};
    float acc[4][4] = {};

    for (int kt = 0; kt < 2; ++kt) {
        const int hb = hs * 64 + kt * 32;
        // stage: each thread reads 8 halves (16B) of one row, repacks into 4 h-pairs
        {
            const int row = tid >> 2;
            const int hc = (tid & 3) * 8;
            const int hp = hc >> 1;
            f16x8 av = *(const f16x8*)&CI[(i0 + row) * 512 + hb + hc];
            As2[(hp + 0) * SC_STR + row] = __builtin_shufflevector(av, av, 0, 1);
            As2[(hp + 1) * SC_STR + row] = __builtin_shufflevector(av, av, 2, 3);
            As2[(hp + 2) * SC_STR + row] = __builtin_shufflevector(av, av, 4, 5);
            As2[(hp + 3) * SC_STR + row] = __builtin_shufflevector(av, av, 6, 7);
            f16x8 bv = *(const f16x8*)&CJ[(j0 + row) * 512 + hb + hc];
            Bs2[(hp + 0) * SC_STR + row] = __builtin_shufflevector(bv, bv, 0, 1);
            Bs2[(hp + 1) * SC_STR + row] = __builtin_shufflevector(bv, bv, 2, 3);
            Bs2[(hp + 2) * SC_STR + row] = __builtin_shufflevector(bv, bv, 4, 5);
            Bs2[(hp + 3) * SC_STR + row] = __builtin_shufflevector(bv, bv, 6, 7);
        }
        if (tid < 16) {
            float2 w = *(const float2*)&w1[hb + 2 * tid];
            f16x2 wp = {(_Float16)w.x, (_Float16)w.y};
            Ws2[tid] = wp;
        }
        __syncthreads();
        #pragma unroll
        for (int k = 0; k < 16; ++k) {
            f16x8 a8 = *(const f16x8*)&As2[k * SC_STR + 4 * ty];
            f16x8 b8 = *(const f16x8*)&Bs2[k * SC_STR + 4 * tx];
            const f16x2 w = Ws2[k];
            f16x2 ap[4] = { __builtin_shufflevector(a8, a8, 0, 1),
                            __builtin_shufflevector(a8, a8, 2, 3),
                            __builtin_shufflevector(a8, a8, 4, 5),
                            __builtin_shufflevector(a8, a8, 6, 7) };
            f16x2 bp[4] = { __builtin_shufflevector(b8, b8, 0, 1),
                            __builtin_shufflevector(b8, b8, 2, 3),
                            __builtin_shufflevector(b8, b8, 4, 5),
                            __builtin_shufflevector(b8, b8, 6, 7) };
            #pragma unroll
            for (int ii = 0; ii < 4; ++ii)
                #pragma unroll
                for (int jj = 0; jj < 4; ++jj) {
                    f16x2 s = ap[ii] + bp[jj];
                    s = __builtin_elementwise_max(s, fz);
                    acc[ii][jj] = __builtin_amdgcn_fdot2(s, w, acc[ii][jj], false);
                }
        }
        __syncthreads();
    }
    _Float16* outp = Ppart + (size_t)hs * 512 * 512;
    #pragma unroll
    for (int ii = 0; ii < 4; ++ii) {
        f16x4 v = { (_Float16)acc[ii][0], (_Float16)acc[ii][1],
                    (_Float16)acc[ii][2], (_Float16)acc[ii][3] };
        *(f16x4*)&outp[(i0 + 4 * ty + ii) * 512 + j0 + 4 * tx] = v;
    }
}

// ---------------------------------------------------------------------------
// Kernel 3: reduce 8 f16 P-partials, row softmax -> Awb[i][j] (f16). grid(512), block 256.
__global__ __launch_bounds__(256) void k_softmax(const _Float16* __restrict__ Ppart,
                                                 _Float16* __restrict__ Awb) {
    const int i = blockIdx.x;
    const int tid = threadIdx.x;
    float p0 = 0.f, p1 = 0.f;
    #pragma unroll
    for (int s = 0; s < 8; ++s) {
        p0 += (float)Ppart[s * 262144 + i * 512 + tid];
        p1 += (float)Ppart[s * 262144 + i * 512 + tid + 256];
    }
    __shared__ float red[256];
    red[tid] = fmaxf(p0, p1);
    __syncthreads();
    for (int s = 128; s > 0; s >>= 1) {
        if (tid < s) red[tid] = fmaxf(red[tid], red[tid + s]);
        __syncthreads();
    }
    const float m = red[0];
    __syncthreads();
    const float e0 = __expf(p0 - m);
    const float e1 = __expf(p1 - m);
    red[tid] = e0 + e1;
    __syncthreads();
    for (int s = 128; s > 0; s >>= 1) {
        if (tid < s) red[tid] += red[tid + s];
        __syncthreads();
    }
    const float inv = 1.0f / red[0];
    Awb[i * 512 + tid] = (_Float16)(e0 * inv);
    Awb[i * 512 + tid + 256] = (_Float16)(e1 * inv);
}

// ---------------------------------------------------------------------------
// Kernel 4: out = Aw @ he via f16 MFMA. 1 wave per 16x32 tile.
// grid (16 d-tiles, 32 i-tiles), block 64.
__global__ __launch_bounds__(64) void k_outM(const _Float16* __restrict__ Awb,
                                             const _Float16* __restrict__ hebT,
                                             float* __restrict__ outp) {
    const int l = threadIdx.x;
    const int d0 = blockIdx.x * 32;
    const int i0 = blockIdx.y * 16;
    const int r16 = l & 15;
    const int k0l = (l >> 4) * 8;

    f32x4 acc[2] = {};
    const _Float16* pa  = Awb  + (i0 + r16) * 512;
    const _Float16* pb0 = hebT + (d0 + r16) * 512;
    const _Float16* pb1 = hebT + (d0 + 16 + r16) * 512;

    #pragma unroll
    for (int ks = 0; ks < 16; ++ks) {
        const int k0 = ks * 32 + k0l;
        f16x8 a  = *(const f16x8*)(pa + k0);
        f16x8 b0 = *(const f16x8*)(pb0 + k0);
        f16x8 b1 = *(const f16x8*)(pb1 + k0);
        acc[0] = __builtin_amdgcn_mfma_f32_16x16x32_f16(a, b0, acc[0], 0, 0, 0);
        acc[1] = __builtin_amdgcn_mfma_f32_16x16x32_f16(a, b1, acc[1], 0, 0, 0);
    }
    const int orow = (l >> 4) * 4;
    #pragma unroll
    for (int tj = 0; tj < 2; ++tj)
        #pragma unroll
        for (int r = 0; r < 4; ++r)
            outp[(i0 + orow + r) * 512 + d0 + tj * 16 + r16] = acc[tj][r];
}

extern "C" void kernel_launch(void* const* d_in, const int* in_sizes, int n_in,
                              void* d_out, int out_size, void* d_ws, size_t ws_size,
                              hipStream_t stream) {
    const float* he = (const float*)d_in[0];   // (512, 512)
    const float* w0 = (const float*)d_in[1];   // (512, 1024)
    const float* b0 = (const float*)d_in[2];   // (512,)
    const float* w1 = (const float*)d_in[3];   // (1, 512)
    // d_in[4] = W1_b: softmax-invariant, intentionally unused.
    float* outp = (float*)d_out;               // (512, 512)

    _Float16* Ppart = (_Float16*)d_ws;                      // 8*512*512 f16
    _Float16* CI = Ppart + 8 * 512 * 512;                   // 512*512 f16
    _Float16* CJ = CI + 512 * 512;                          // 512*512 f16
    unsigned short* heb  = (unsigned short*)(CJ + 512 * 512);  // 512*512 bf16
    _Float16* hebT = (_Float16*)(heb + 512 * 512);          // 512*512 f16
    unsigned short* w0b  = (unsigned short*)(hebT + 512 * 512); // 512*1024 bf16
    _Float16* Awb  = (_Float16*)(w0b + 512 * 1024);         // 512*512 f16

    k_prep   <<<dim3(8, 8, 3), 256, 0, stream>>>(he, w0, heb, hebT, w0b);
    k_preA   <<<dim3(32, 16),  64,  0, stream>>>(heb, w0b, b0, CI, CJ);
    k_score  <<<dim3(8, 8, 8), 256, 0, stream>>>(CI, CJ, w1, Ppart);
    k_softmax<<<dim3(512),     256, 0, stream>>>(Ppart, Awb);
    k_outM   <<<dim3(16, 32),  64,  0, stream>>>(Awb, hebT, outp);
}